// Round 14
// baseline (621.051 us; speedup 1.0000x reference)
//
#include <hip/hip_runtime.h>
#include <hip/hip_bf16.h>
#include <hip/hip_cooperative_groups.h>

namespace cg = cooperative_groups;

#define DD 128
#define BN_EPS 1e-5f
#define BINSHIFT 8
#define EPB 8192   // edges per block-unit in binning phase
#define CAP 6144   // padded slots per 256-node bin

typedef __attribute__((ext_vector_type(8))) short bf16x8;
typedef __attribute__((ext_vector_type(4))) float f32x4;

static __device__ __forceinline__ size_t rowoff(int r) { return (size_t)r * DD; }

static __device__ __forceinline__ ushort f2bf(float f) {
  __hip_bfloat16 h = __float2bfloat16(f);
  return __builtin_bit_cast(ushort, h);
}
static __device__ __forceinline__ float bf_lo(unsigned u) { return __uint_as_float(u << 16); }
static __device__ __forceinline__ float bf_hi(unsigned u) { return __uint_as_float(u & 0xffff0000u); }

// Single cooperative kernel; phases [phase_lo..phase_hi]; grid.sync between
// phases iff coop. Every phase is grid-strided (any grid size correct).
// LDS pool 24KB -> 6 blocks/CU -> 24 waves/CU (aggregate's measured sweet spot).
__global__ __launch_bounds__(256, 6) void k_mega(
    const int* __restrict__ src, const int* __restrict__ dst,
    const float* __restrict__ x, const float* __restrict__ W,
    const float* __restrict__ bvec, const float* __restrict__ gamma,
    const float* __restrict__ beta,
    int* __restrict__ gcursor, unsigned* __restrict__ stg,
    ushort* __restrict__ Wb, int* __restrict__ ssrc,
    int* __restrict__ offs, int* __restrict__ oend,
    float* __restrict__ dinv, ushort* __restrict__ xwb,
    float* __restrict__ out, ushort* __restrict__ aggb,
    float* __restrict__ stats,
    int N, int E, int NB, int nchunk, float invN,
    int phase_lo, int phase_hi, int coop) {
  __shared__ __align__(16) char pool[24576];
  int t = threadIdx.x;

  for (int ph = phase_lo; ph <= phase_hi; ++ph) {
    if (ph == 0) {
      // ---- phase 0: bin-scatter chunks [0,nchunk) + convW unit [nchunk] ----
      int* hist = (int*)pool;
      int* base = (int*)(pool + 4096);
      for (int u = blockIdx.x; u <= nchunk; u += gridDim.x) {
        if (u == nchunk) {
#pragma unroll
          for (int i = 0; i < 16; ++i) {
            int f = i * 256 + t;
            int row = f >> 5, c4 = f & 31;
            float4 w = reinterpret_cast<const float4*>(W)[f];
            ushort4 p = make_ushort4(f2bf(w.x), f2bf(w.y), f2bf(w.z), f2bf(w.w));
            int chunk = (c4 >> 1) ^ (row & 7);
            *reinterpret_cast<ushort4*>(reinterpret_cast<char*>(Wb) + row * 256 +
                                        chunk * 16 + (c4 & 1) * 8) = p;
          }
        } else {
          long long e0 = (long long)u * EPB;
          int eend = (int)((e0 + EPB < E) ? e0 + EPB : E);
          for (int i = t; i < NB; i += 256) hist[i] = 0;
          __syncthreads();
          for (int i = (int)e0 + t; i < eend; i += 256)
            atomicAdd(&hist[dst[i] >> BINSHIFT], 1);
          __syncthreads();
          for (int i = t; i < NB; i += 256) {
            int c = hist[i];
            base[i] = c ? (i * CAP + atomicAdd(&gcursor[i], c)) : 0;
            hist[i] = 0;
          }
          __syncthreads();
          for (int i = (int)e0 + t; i < eend; i += 256) {
            int d = dst[i];
            int bin = d >> BINSHIFT;
            unsigned v = ((unsigned)(d & 255) << 24) | (unsigned)src[i];
            int p = atomicAdd(&hist[bin], 1);
            stg[base[bin] + p] = v;
          }
          __syncthreads();
        }
      }
    } else if (ph == 1) {
      // ---- phase 1: per-bin fine sort; emits offs/oend/dinv ----
      int* hist = (int*)pool;
      int* scanb = (int*)(pool + 1024);
      for (int b = blockIdx.x; b < NB; b += gridDim.x) {
        int beg = b * CAP;
        int end = beg + gcursor[b];
        int nloc = N - b * 256;
        if (nloc > 256) nloc = 256;
        hist[t] = 0;
        __syncthreads();
        for (int i = beg + t; i < end; i += 256) atomicAdd(&hist[stg[i] >> 24], 1);
        __syncthreads();
        int h = hist[t];
        scanb[t] = h;
        __syncthreads();
        for (int off = 1; off < 256; off <<= 1) {
          int u2 = (t >= off) ? scanb[t - off] : 0;
          __syncthreads();
          scanb[t] += u2;
          __syncthreads();
        }
        int myexcl = scanb[t] - h;
        __syncthreads();
        scanb[t] = myexcl;
        hist[t] = 0;
        int node = b * 256 + t;
        if (t < nloc) {
          offs[node] = beg + myexcl;
          oend[node] = beg + myexcl + h;
          dinv[node] = h > 0 ? rsqrtf((float)h) : 0.f;
        }
        __syncthreads();
        for (int i = beg + t; i < end; i += 256) {
          unsigned v = stg[i];
          int loc = v >> 24;
          int p = atomicAdd(&hist[loc], 1);
          ssrc[beg + scanb[loc] + p] = (int)(v & 0xFFFFFFu);
        }
        __syncthreads();
      }
    } else if (ph == 2) {
      // ---- phase 2: GEMM, x-frags from global regs, W in 2 LDS halves ----
      int wid = t >> 6, lane = t & 63;
      int kgrp = lane >> 4;
      int ntiles = (N + 63) >> 6;
      const float4* x4g = reinterpret_cast<const float4*>(x);
      for (int tile = blockIdx.x; tile < ntiles; tile += gridDim.x) {
        int node = tile * 64 + wid * 16 + (lane & 15);
        bool valid = node < N;
        bf16x8 xf[4];
#pragma unroll
        for (int ks = 0; ks < 4; ++ks) {
          int c = ks * 4 + kgrp;
          float4 lo = make_float4(0.f, 0.f, 0.f, 0.f), hi = lo;
          if (valid) {
            lo = x4g[(size_t)node * 32 + c * 2];
            hi = x4g[(size_t)node * 32 + c * 2 + 1];
          }
          union { ushort us[8]; bf16x8 v; } pk;
          pk.us[0] = f2bf(lo.x); pk.us[1] = f2bf(lo.y);
          pk.us[2] = f2bf(lo.z); pk.us[3] = f2bf(lo.w);
          pk.us[4] = f2bf(hi.x); pk.us[5] = f2bf(hi.y);
          pk.us[6] = f2bf(hi.z); pk.us[7] = f2bf(hi.w);
          xf[ks] = pk.v;
        }
        float sc = valid ? dinv[node] : 0.f;
#pragma unroll
        for (int half = 0; half < 2; ++half) {
          __syncthreads();  // Bbuf safe to overwrite
          {
            const char* gW = reinterpret_cast<const char*>(Wb) + half * 16384;
#pragma unroll
            for (int i2 = 0; i2 < 4; ++i2) {
              int off = i2 * 4096 + wid * 1024;
              __builtin_amdgcn_global_load_lds(
                  (const __attribute__((address_space(1))) void*)(gW + off + lane * 16),
                  (__attribute__((address_space(3))) void*)(pool + off), 16, 0, 0);
            }
          }
          __syncthreads();
          f32x4 acc[4];
#pragma unroll
          for (int cf = 0; cf < 4; ++cf) acc[cf] = (f32x4){0.f, 0.f, 0.f, 0.f};
#pragma unroll
          for (int ks = 0; ks < 4; ++ks) {
            int c = ks * 4 + kgrp;
#pragma unroll
            for (int cf = 0; cf < 4; ++cf) {
              int rl = cf * 16 + (lane & 15);  // local channel row
              bf16x8 wf = *reinterpret_cast<const bf16x8*>(
                  pool + rl * 256 + ((c ^ (rl & 7)) * 16));
              acc[cf] = __builtin_amdgcn_mfma_f32_16x16x32_bf16(wf, xf[ks], acc[cf], 0, 0, 0);
            }
          }
          if (valid) {
            char* orow = reinterpret_cast<char*>(xwb + rowoff(node) + half * 64 +
                                                 (lane >> 4) * 4);
#pragma unroll
            for (int cf = 0; cf < 4; ++cf) {
              unsigned lo2 = (unsigned)f2bf(acc[cf][0] * sc) |
                             ((unsigned)f2bf(acc[cf][1] * sc) << 16);
              unsigned hi2 = (unsigned)f2bf(acc[cf][2] * sc) |
                             ((unsigned)f2bf(acc[cf][3] * sc) << 16);
              *reinterpret_cast<uint2*>(orow + cf * 32) = make_uint2(lo2, hi2);
            }
          }
        }
      }
    } else if (ph == 3) {
      // ---- phase 3: segmented aggregate + fused BN-stats ----
      float* red = (float*)pool;
      int wid = t >> 6, lane = t & 63;
      float bc0 = bvec[2 * lane], bc1 = bvec[2 * lane + 1];
      float s0 = 0.f, q0 = 0.f, s1 = 0.f, q1 = 0.f;
      const unsigned laneb = lane * 2;
      for (int d = blockIdx.x * 4 + wid; d < N; d += gridDim.x * 4) {
        int off = offs[d], end = oend[d];
        float a0 = 0.f, a1 = 0.f, b0 = 0.f, b1 = 0.f;
        float c0 = 0.f, c1 = 0.f, e0 = 0.f, e1 = 0.f;
        int j = off;
        for (; j + 8 <= end; j += 8) {
          int sA = ssrc[j],     sB = ssrc[j + 1], sC = ssrc[j + 2], sD = ssrc[j + 3];
          int sE = ssrc[j + 4], sF = ssrc[j + 5], sG = ssrc[j + 6], sH = ssrc[j + 7];
          unsigned v0 = *reinterpret_cast<const unsigned*>(xwb + (size_t)sA * DD + laneb);
          unsigned v1 = *reinterpret_cast<const unsigned*>(xwb + (size_t)sB * DD + laneb);
          unsigned v2 = *reinterpret_cast<const unsigned*>(xwb + (size_t)sC * DD + laneb);
          unsigned v3 = *reinterpret_cast<const unsigned*>(xwb + (size_t)sD * DD + laneb);
          unsigned v4 = *reinterpret_cast<const unsigned*>(xwb + (size_t)sE * DD + laneb);
          unsigned v5 = *reinterpret_cast<const unsigned*>(xwb + (size_t)sF * DD + laneb);
          unsigned v6 = *reinterpret_cast<const unsigned*>(xwb + (size_t)sG * DD + laneb);
          unsigned v7 = *reinterpret_cast<const unsigned*>(xwb + (size_t)sH * DD + laneb);
          a0 += bf_lo(v0); a1 += bf_hi(v0);
          b0 += bf_lo(v1); b1 += bf_hi(v1);
          c0 += bf_lo(v2); c1 += bf_hi(v2);
          e0 += bf_lo(v3); e1 += bf_hi(v3);
          a0 += bf_lo(v4); a1 += bf_hi(v4);
          b0 += bf_lo(v5); b1 += bf_hi(v5);
          c0 += bf_lo(v6); c1 += bf_hi(v6);
          e0 += bf_lo(v7); e1 += bf_hi(v7);
        }
        if (j + 4 <= end) {
          int sA = ssrc[j], sB = ssrc[j + 1], sC = ssrc[j + 2], sD = ssrc[j + 3];
          unsigned v0 = *reinterpret_cast<const unsigned*>(xwb + (size_t)sA * DD + laneb);
          unsigned v1 = *reinterpret_cast<const unsigned*>(xwb + (size_t)sB * DD + laneb);
          unsigned v2 = *reinterpret_cast<const unsigned*>(xwb + (size_t)sC * DD + laneb);
          unsigned v3 = *reinterpret_cast<const unsigned*>(xwb + (size_t)sD * DD + laneb);
          a0 += bf_lo(v0); a1 += bf_hi(v0);
          b0 += bf_lo(v1); b1 += bf_hi(v1);
          c0 += bf_lo(v2); c1 += bf_hi(v2);
          e0 += bf_lo(v3); e1 += bf_hi(v3);
          j += 4;
        }
        for (; j < end; ++j) {
          int sA = ssrc[j];
          unsigned v0 = *reinterpret_cast<const unsigned*>(xwb + (size_t)sA * DD + laneb);
          a0 += bf_lo(v0); a1 += bf_hi(v0);
        }
        float dd = dinv[d];
        float r0 = ((a0 + b0) + (c0 + e0)) * dd;
        float r1 = ((a1 + b1) + (c1 + e1)) * dd;
        if (aggb) {
          unsigned pk = (unsigned)f2bf(r0) | ((unsigned)f2bf(r1) << 16);
          reinterpret_cast<unsigned*>(aggb + rowoff(d))[lane] = pk;
        } else {
          reinterpret_cast<float2*>(out + rowoff(d))[lane] = make_float2(r0, r1);
        }
        float t0 = r0 + bc0, t1 = r1 + bc1;
        s0 += t0; q0 += t0 * t0;
        s1 += t1; q1 += t1 * t1;
      }
      float4* rw = reinterpret_cast<float4*>(red);
      rw[wid * 64 + lane] = make_float4(s0, q0, s1, q1);
      __syncthreads();
      {
        float v = red[t] + red[256 + t] + red[512 + t] + red[768 + t];
        int ln = t >> 2, k = t & 3;
        int col = 2 * ln + (k >> 1);
        int rep = blockIdx.x & 7;
        atomicAdd(&stats[rep * 256 + (k & 1) * 128 + col], v);
      }
      __syncthreads();
    } else {
      // ---- phase 4: out = relu((agg + b - mu)*rstd*gamma + beta) + x ----
      float* muS = (float*)pool;
      float* rsS = (float*)(pool + 512);
      if (t < DD) {
        float s = 0.f, q = 0.f;
#pragma unroll
        for (int rep = 0; rep < 8; ++rep) {
          s += stats[rep * 256 + t];
          q += stats[rep * 256 + 128 + t];
        }
        float mu = s * invN;
        float var = q * invN - mu * mu;
        muS[t] = mu;
        rsS[t] = rsqrtf(var + BN_EPS);
      }
      __syncthreads();
      long long i = (long long)blockIdx.x * 256 + t;
      long long stride = (long long)gridDim.x * 256;
      long long total = (long long)N * (DD / 4);
      const float4* x4 = reinterpret_cast<const float4*>(x);
      float4* o4 = reinterpret_cast<float4*>(out);
      const float4* b4 = reinterpret_cast<const float4*>(bvec);
      const float4* g4 = reinterpret_cast<const float4*>(gamma);
      const float4* be4 = reinterpret_cast<const float4*>(beta);
      const float4* muL = reinterpret_cast<const float4*>(muS);
      const float4* rsL = reinterpret_cast<const float4*>(rsS);
      for (; i < total; i += stride) {
        int c4 = (int)(i & (DD / 4 - 1));
        float4 v;
        if (aggb) {
          uint2 av = reinterpret_cast<const uint2*>(aggb)[i];
          v = make_float4(bf_lo(av.x), bf_hi(av.x), bf_lo(av.y), bf_hi(av.y));
        } else {
          v = o4[i];
        }
        float4 xv = x4[i];
        float4 bb = b4[c4], gg = g4[c4], be = be4[c4], mm = muL[c4], rr = rsL[c4];
        float4 o;
        o.x = fmaxf((v.x + bb.x - mm.x) * rr.x * gg.x + be.x, 0.f) + xv.x;
        o.y = fmaxf((v.y + bb.y - mm.y) * rr.y * gg.y + be.y, 0.f) + xv.y;
        o.z = fmaxf((v.z + bb.z - mm.z) * rr.z * gg.z + be.z, 0.f) + xv.z;
        o.w = fmaxf((v.w + bb.w - mm.w) * rr.w * gg.w + be.w, 0.f) + xv.w;
        o4[i] = o;
      }
    }
    if (coop && ph < phase_hi) cg::this_grid().sync();
  }
}

extern "C" void kernel_launch(void* const* d_in, const int* in_sizes, int n_in,
                              void* d_out, int out_size, void* d_ws, size_t ws_size,
                              hipStream_t stream) {
  const int* ei = (const int*)d_in[1];
  const float* x = (const float*)d_in[0];
  const float* W = (const float*)d_in[2];
  const float* b = (const float*)d_in[3];
  const float* gamma = (const float*)d_in[4];
  const float* beta = (const float*)d_in[5];
  int N = in_sizes[0] / DD;
  int E = in_sizes[1] / 2;
  float* out = (float*)d_out;
  const int* src = ei;
  const int* dst = ei + E;
  int NB = (N + 255) >> BINSHIFT;

  // workspace layout (as R13)
  ushort* xwb = (ushort*)d_ws;
  ushort* Wb = xwb + (size_t)N * DD;
  unsigned* stg = (unsigned*)(Wb + DD * DD);
  int* ssrc = (int*)(stg + (size_t)NB * CAP);
  int* offs = ssrc + (size_t)NB * CAP;
  int* oend = offs + N;
  float* dinv = (float*)(oend + N);
  int* gcursor = (int*)(dinv + N);
  float* stats = (float*)(gcursor + 1024);
  ushort* aggb = (ushort*)(stats + 2048);
  size_t need_aggb = (size_t)((char*)(aggb + (size_t)N * DD) - (char*)d_ws);
  if (ws_size < need_aggb) aggb = nullptr;

  hipMemsetAsync(gcursor, 0, 1024 * sizeof(int) + 2048 * sizeof(float), stream);

  int nchunk = (E + EPB - 1) / EPB;
  float invN = 1.0f / (float)N;

  // grid sizing: co-residency via occupancy query (phases all grid-stride)
  int maxB = 0;
  hipOccupancyMaxActiveBlocksPerMultiprocessor(&maxB, k_mega, 256, 0);
  if (maxB < 1) maxB = 1;
  if (maxB > 6) maxB = 6;
  int nCU = 0;
  hipDeviceGetAttribute(&nCU, hipDeviceAttributeMultiprocessorCount, 0);
  if (nCU < 1) nCU = 256;
  int grid = maxB * nCU;
  if (grid > 2048) grid = 2048;

  int phase_lo = 0, phase_hi = 4, coop = 1;
  void* args[] = {
      (void*)&src, (void*)&dst, (void*)&x, (void*)&W, (void*)&b,
      (void*)&gamma, (void*)&beta,
      (void*)&gcursor, (void*)&stg, (void*)&Wb, (void*)&ssrc,
      (void*)&offs, (void*)&oend, (void*)&dinv, (void*)&xwb,
      (void*)&out, (void*)&aggb, (void*)&stats,
      (void*)&N, (void*)&E, (void*)&NB, (void*)&nchunk, (void*)&invN,
      (void*)&phase_lo, (void*)&phase_hi, (void*)&coop};

  hipError_t err = hipLaunchCooperativeKernel(k_mega, dim3(grid), dim3(256),
                                              args, 0, stream);
  if (err != hipSuccess) {
    // fallback: same kernel, one normal launch per phase (no grid.sync)
    for (int ph = 0; ph < 5; ++ph) {
      k_mega<<<grid, 256, 0, stream>>>(src, dst, x, W, b, gamma, beta,
                                       gcursor, stg, Wb, ssrc, offs, oend,
                                       dinv, xwb, out, aggb, stats,
                                       N, E, NB, nchunk, invN, ph, ph, 0);
    }
  }
}

// Round 15
// 153.569 us; speedup vs baseline: 4.0441x; 4.0441x over previous
//
#include <hip/hip_runtime.h>
#include <hip/hip_bf16.h>

#define DD 128
#define BN_EPS 1e-5f
#define BINSHIFT 8
#define EPB 8192   // edges per block in binning passes (proven optimum)
#define CAP 6144   // padded slots per 256-node bin (mean 4096, sigma 64)

typedef __attribute__((ext_vector_type(8))) short bf16x8;
typedef __attribute__((ext_vector_type(4))) float f32x4;

static __device__ __forceinline__ size_t rowoff(int r) { return (size_t)r * DD; }

static __device__ __forceinline__ ushort f2bf(float f) {
  __hip_bfloat16 h = __float2bfloat16(f);
  return __builtin_bit_cast(ushort, h);
}
static __device__ __forceinline__ float bf_lo(unsigned u) { return __uint_as_float(u << 16); }
static __device__ __forceinline__ float bf_hi(unsigned u) { return __uint_as_float(u & 0xffff0000u); }

// ---- merged: binscatter blocks [0,nchunk) + convW block [nchunk] ----
__global__ __launch_bounds__(256) void k_scatter_convw(const int* __restrict__ src,
                                                       const int* __restrict__ dst,
                                                       int* __restrict__ gcursor,
                                                       unsigned* __restrict__ stg,
                                                       const float* __restrict__ W,
                                                       ushort* __restrict__ Wb,
                                                       int E, int NB, int nchunk) {
  int t = threadIdx.x;
  if (blockIdx.x == (unsigned)nchunk) {
#pragma unroll
    for (int i = 0; i < 16; ++i) {
      int f = i * 256 + t;
      int row = f >> 5, c4 = f & 31;
      float4 w = reinterpret_cast<const float4*>(W)[f];
      ushort4 p = make_ushort4(f2bf(w.x), f2bf(w.y), f2bf(w.z), f2bf(w.w));
      int chunk = (c4 >> 1) ^ (row & 7);
      *reinterpret_cast<ushort4*>(reinterpret_cast<char*>(Wb) + row * 256 +
                                  chunk * 16 + (c4 & 1) * 8) = p;
    }
    return;
  }
  __shared__ int hist[1024];
  __shared__ int base[1024];
  long long e0 = (long long)blockIdx.x * EPB;
  int eend = (int)((e0 + EPB < E) ? e0 + EPB : E);
  for (int i = t; i < NB; i += 256) hist[i] = 0;
  __syncthreads();
  for (int i = (int)e0 + t; i < eend; i += 256) atomicAdd(&hist[dst[i] >> BINSHIFT], 1);
  __syncthreads();
  for (int i = t; i < NB; i += 256) {
    int c = hist[i];
    base[i] = c ? (i * CAP + atomicAdd(&gcursor[i], c)) : 0;
    hist[i] = 0;  // becomes local cursor
  }
  __syncthreads();
  for (int i = (int)e0 + t; i < eend; i += 256) {
    int d = dst[i];
    int bin = d >> BINSHIFT;
    unsigned v = ((unsigned)(d & 255) << 24) | (unsigned)src[i];
    int p = atomicAdd(&hist[bin], 1);
    stg[base[bin] + p] = v;
  }
}

// ---- per-bin fine sort (padded layout); emits offs[], oend[], dinv[] ----
__global__ __launch_bounds__(256) void k_binsort(const unsigned* __restrict__ stg,
                                                 const int* __restrict__ gcursor,
                                                 int* __restrict__ ssrc,
                                                 int* __restrict__ offs,
                                                 int* __restrict__ oend,
                                                 float* __restrict__ dinv,
                                                 int N) {
  __shared__ int hist[256];
  __shared__ int scanb[256];
  int b = blockIdx.x;
  int t = threadIdx.x;
  int beg = b * CAP;
  int end = beg + gcursor[b];
  int nloc = N - b * 256;
  if (nloc > 256) nloc = 256;
  hist[t] = 0;
  __syncthreads();
  for (int i = beg + t; i < end; i += 256) atomicAdd(&hist[stg[i] >> 24], 1);
  __syncthreads();
  int h = hist[t];
  scanb[t] = h;
  __syncthreads();
  for (int off = 1; off < 256; off <<= 1) {
    int u = (t >= off) ? scanb[t - off] : 0;
    __syncthreads();
    scanb[t] += u;
    __syncthreads();
  }
  int myexcl = scanb[t] - h;
  __syncthreads();
  scanb[t] = myexcl;  // exclusive base within bin
  hist[t] = 0;        // becomes cursor
  int node = b * 256 + t;
  if (t < nloc) {
    offs[node] = beg + myexcl;
    oend[node] = beg + myexcl + h;
    dinv[node] = h > 0 ? rsqrtf((float)h) : 0.f;
  }
  __syncthreads();
  for (int i = beg + t; i < end; i += 256) {
    unsigned v = stg[i];
    int loc = v >> 24;
    int p = atomicAdd(&hist[loc], 1);
    ssrc[beg + scanb[loc] + p] = (int)(v & 0xFFFFFFu);
  }
}

// ---- MFMA GEMM (BM=64): xwb[n][c] = bf16( dinv[n] * dot(x[n][:], W[c][:]) )
// 48KB LDS -> 3 blocks/CU. B staged from pre-swizzled Wb via global_load_lds.
__global__ __launch_bounds__(256) void k_gemm_mfma(const float* __restrict__ x,
                                                   const ushort* __restrict__ Wb,
                                                   const float* __restrict__ dinv,
                                                   ushort* __restrict__ xwb, int N) {
  __shared__ ushort Abuf[64 * 128];
  __shared__ ushort Bbuf[128 * 128];
  int t = threadIdx.x;
  int brow = blockIdx.x * 64;
  int wid = t >> 6, lane = t & 63;

  {
    const char* gW = reinterpret_cast<const char*>(Wb);
    char* lB = reinterpret_cast<char*>(Bbuf);
#pragma unroll
    for (int i = 0; i < 8; ++i) {
      int off = i * 4096 + wid * 1024;
      __builtin_amdgcn_global_load_lds(
          (const __attribute__((address_space(1))) void*)(gW + off + lane * 16),
          (__attribute__((address_space(3))) void*)(lB + off), 16, 0, 0);
    }
  }
  // stage x rows -> Abuf (bf16, swizzled, zero-fill OOB): 64 rows * 32 float4
#pragma unroll
  for (int i = 0; i < 8; ++i) {
    int f = i * 256 + t;
    int row = f >> 5, c4 = f & 31;
    int grow = brow + row;
    float4 v = make_float4(0.f, 0.f, 0.f, 0.f);
    if (grow < N) v = reinterpret_cast<const float4*>(x)[(size_t)grow * 32 + c4];
    ushort4 p = make_ushort4(f2bf(v.x), f2bf(v.y), f2bf(v.z), f2bf(v.w));
    int chunk = (c4 >> 1) ^ (row & 7);
    *reinterpret_cast<ushort4*>(reinterpret_cast<char*>(Abuf) + row * 256 +
                                chunk * 16 + (c4 & 1) * 8) = p;
  }
  __syncthreads();

  int kgrp = lane >> 4;
  int r0 = wid * 16 + (lane & 15);
  f32x4 acc[8];
#pragma unroll
  for (int cf = 0; cf < 8; ++cf) acc[cf] = (f32x4){0.f, 0.f, 0.f, 0.f};

  const char* Ab = reinterpret_cast<const char*>(Abuf);
  const char* Bb = reinterpret_cast<const char*>(Bbuf);
#pragma unroll
  for (int ks = 0; ks < 4; ++ks) {
    int c = ks * 4 + kgrp;
    bf16x8 a0 = *reinterpret_cast<const bf16x8*>(Ab + r0 * 256 + ((c ^ (r0 & 7)) * 16));
#pragma unroll
    for (int cf = 0; cf < 8; ++cf) {
      int bc = cf * 16 + (lane & 15);
      bf16x8 bv = *reinterpret_cast<const bf16x8*>(Bb + bc * 256 + ((c ^ (bc & 7)) * 16));
      acc[cf] = __builtin_amdgcn_mfma_f32_16x16x32_bf16(a0, bv, acc[cf], 0, 0, 0);
    }
  }

#pragma unroll
  for (int j = 0; j < 4; ++j) {
    int gr = brow + wid * 16 + (lane >> 4) * 4 + j;
    if (gr < N) {
      float sc = dinv[gr];
      ushort* orow = xwb + (size_t)gr * DD + (lane & 15);
#pragma unroll
      for (int cf = 0; cf < 8; ++cf) orow[cf * 16] = f2bf(acc[cf][j] * sc);
    }
  }
}

// ---- segmented aggregate + fused BN-stats (R9-proven) ----
__global__ __launch_bounds__(256) void k_aggregate(const int* __restrict__ offs,
                                                   const int* __restrict__ oend,
                                                   const int* __restrict__ ssrc,
                                                   const float* __restrict__ dinv,
                                                   const float* __restrict__ bvec,
                                                   const ushort* __restrict__ xwb,
                                                   float* __restrict__ agg,
                                                   ushort* __restrict__ aggb,
                                                   float* __restrict__ stats, int N) {
  __shared__ float red[1024];
  int t = threadIdx.x;
  int wid = t >> 6, lane = t & 63;
  float bc0 = bvec[2 * lane], bc1 = bvec[2 * lane + 1];
  float s0 = 0.f, q0 = 0.f, s1 = 0.f, q1 = 0.f;
  const unsigned laneb = lane * 2;

  for (int d = blockIdx.x * 4 + wid; d < N; d += gridDim.x * 4) {
    int off = offs[d], end = oend[d];
    float a0 = 0.f, a1 = 0.f, b0 = 0.f, b1 = 0.f;
    float c0 = 0.f, c1 = 0.f, e0 = 0.f, e1 = 0.f;
    int j = off;
    for (; j + 8 <= end; j += 8) {
      int sA = ssrc[j],     sB = ssrc[j + 1], sC = ssrc[j + 2], sD = ssrc[j + 3];
      int sE = ssrc[j + 4], sF = ssrc[j + 5], sG = ssrc[j + 6], sH = ssrc[j + 7];
      unsigned v0 = *reinterpret_cast<const unsigned*>(xwb + (size_t)sA * DD + laneb);
      unsigned v1 = *reinterpret_cast<const unsigned*>(xwb + (size_t)sB * DD + laneb);
      unsigned v2 = *reinterpret_cast<const unsigned*>(xwb + (size_t)sC * DD + laneb);
      unsigned v3 = *reinterpret_cast<const unsigned*>(xwb + (size_t)sD * DD + laneb);
      unsigned v4 = *reinterpret_cast<const unsigned*>(xwb + (size_t)sE * DD + laneb);
      unsigned v5 = *reinterpret_cast<const unsigned*>(xwb + (size_t)sF * DD + laneb);
      unsigned v6 = *reinterpret_cast<const unsigned*>(xwb + (size_t)sG * DD + laneb);
      unsigned v7 = *reinterpret_cast<const unsigned*>(xwb + (size_t)sH * DD + laneb);
      a0 += bf_lo(v0); a1 += bf_hi(v0);
      b0 += bf_lo(v1); b1 += bf_hi(v1);
      c0 += bf_lo(v2); c1 += bf_hi(v2);
      e0 += bf_lo(v3); e1 += bf_hi(v3);
      a0 += bf_lo(v4); a1 += bf_hi(v4);
      b0 += bf_lo(v5); b1 += bf_hi(v5);
      c0 += bf_lo(v6); c1 += bf_hi(v6);
      e0 += bf_lo(v7); e1 += bf_hi(v7);
    }
    if (j + 4 <= end) {
      int sA = ssrc[j], sB = ssrc[j + 1], sC = ssrc[j + 2], sD = ssrc[j + 3];
      unsigned v0 = *reinterpret_cast<const unsigned*>(xwb + (size_t)sA * DD + laneb);
      unsigned v1 = *reinterpret_cast<const unsigned*>(xwb + (size_t)sB * DD + laneb);
      unsigned v2 = *reinterpret_cast<const unsigned*>(xwb + (size_t)sC * DD + laneb);
      unsigned v3 = *reinterpret_cast<const unsigned*>(xwb + (size_t)sD * DD + laneb);
      a0 += bf_lo(v0); a1 += bf_hi(v0);
      b0 += bf_lo(v1); b1 += bf_hi(v1);
      c0 += bf_lo(v2); c1 += bf_hi(v2);
      e0 += bf_lo(v3); e1 += bf_hi(v3);
      j += 4;
    }
    for (; j < end; ++j) {
      int sA = ssrc[j];
      unsigned v0 = *reinterpret_cast<const unsigned*>(xwb + (size_t)sA * DD + laneb);
      a0 += bf_lo(v0); a1 += bf_hi(v0);
    }
    float dd = dinv[d];
    float r0 = ((a0 + b0) + (c0 + e0)) * dd;
    float r1 = ((a1 + b1) + (c1 + e1)) * dd;
    if (aggb) {
      unsigned pk = (unsigned)f2bf(r0) | ((unsigned)f2bf(r1) << 16);
      reinterpret_cast<unsigned*>(aggb + rowoff(d))[lane] = pk;
    } else {
      reinterpret_cast<float2*>(agg + rowoff(d))[lane] = make_float2(r0, r1);
    }
    float t0 = r0 + bc0, t1 = r1 + bc1;
    s0 += t0; q0 += t0 * t0;
    s1 += t1; q1 += t1 * t1;
  }

  float4* rw = reinterpret_cast<float4*>(red);
  rw[wid * 64 + lane] = make_float4(s0, q0, s1, q1);
  __syncthreads();
  {
    float v = red[t] + red[256 + t] + red[512 + t] + red[768 + t];
    int ln = t >> 2, k = t & 3;  // k: 0=s0 1=q0 2=s1 3=q1
    int col = 2 * ln + (k >> 1);
    int rep = blockIdx.x & 7;
    atomicAdd(&stats[rep * 256 + (k & 1) * 128 + col], v);
  }
}

// ---- out = relu((agg + b - mu) * rstd * gamma + beta) + x ----
__global__ __launch_bounds__(256) void k_final(float* __restrict__ out,
                                               const ushort* __restrict__ aggb,
                                               const float* __restrict__ x,
                                               const float* __restrict__ b,
                                               const float* __restrict__ gamma,
                                               const float* __restrict__ beta,
                                               const float* __restrict__ stats,
                                               float invN, int N) {
  __shared__ float muS[DD], rsS[DD];
  int t = threadIdx.x;
  if (t < DD) {
    float s = 0.f, q = 0.f;
#pragma unroll
    for (int rep = 0; rep < 8; ++rep) {
      s += stats[rep * 256 + t];
      q += stats[rep * 256 + 128 + t];
    }
    float mu = s * invN;
    float var = q * invN - mu * mu;
    muS[t] = mu;
    rsS[t] = rsqrtf(var + BN_EPS);
  }
  __syncthreads();

  long long i = (long long)blockIdx.x * 256 + threadIdx.x;
  long long stride = (long long)gridDim.x * 256;
  long long total = (long long)N * (DD / 4);
  const float4* __restrict__ x4 = reinterpret_cast<const float4*>(x);
  float4* __restrict__ o4 = reinterpret_cast<float4*>(out);
  const float4* __restrict__ b4 = reinterpret_cast<const float4*>(b);
  const float4* __restrict__ g4 = reinterpret_cast<const float4*>(gamma);
  const float4* __restrict__ be4 = reinterpret_cast<const float4*>(beta);
  const float4* muL = reinterpret_cast<const float4*>(muS);
  const float4* rsL = reinterpret_cast<const float4*>(rsS);
  for (; i < total; i += stride) {
    int c4 = (int)(i & (DD / 4 - 1));
    float4 v;
    if (aggb) {
      uint2 av = reinterpret_cast<const uint2*>(aggb)[i];
      v = make_float4(bf_lo(av.x), bf_hi(av.x), bf_lo(av.y), bf_hi(av.y));
    } else {
      v = o4[i];
    }
    float4 xv = x4[i];
    float4 bb = b4[c4], gg = g4[c4], be = be4[c4], mm = muL[c4], rr = rsL[c4];
    float4 o;
    o.x = fmaxf((v.x + bb.x - mm.x) * rr.x * gg.x + be.x, 0.f) + xv.x;
    o.y = fmaxf((v.y + bb.y - mm.y) * rr.y * gg.y + be.y, 0.f) + xv.y;
    o.z = fmaxf((v.z + bb.z - mm.z) * rr.z * gg.z + be.z, 0.f) + xv.z;
    o.w = fmaxf((v.w + bb.w - mm.w) * rr.w * gg.w + be.w, 0.f) + xv.w;
    o4[i] = o;
  }
}

extern "C" void kernel_launch(void* const* d_in, const int* in_sizes, int n_in,
                              void* d_out, int out_size, void* d_ws, size_t ws_size,
                              hipStream_t stream) {
  const float* x = (const float*)d_in[0];
  const int* ei = (const int*)d_in[1];
  const float* W = (const float*)d_in[2];
  const float* b = (const float*)d_in[3];
  const float* gamma = (const float*)d_in[4];
  const float* beta = (const float*)d_in[5];
  int N = in_sizes[0] / DD;
  int E = in_sizes[1] / 2;
  float* out = (float*)d_out;
  const int* src = ei;
  const int* dst = ei + E;
  int NB = (N + 255) >> BINSHIFT;  // assumes N <= 262144 (NB <= 1024)

  // workspace layout
  ushort* xwb = (ushort*)d_ws;                        // N*DD bf16      (25.6MB)
  ushort* Wb = xwb + (size_t)N * DD;                  // 128*128 bf16   (32KB)
  unsigned* stg = (unsigned*)(Wb + DD * DD);          // NB*CAP         (9.6MB)
  int* ssrc = (int*)(stg + (size_t)NB * CAP);         // NB*CAP         (9.6MB)
  int* offs = ssrc + (size_t)NB * CAP;                // N
  int* oend = offs + N;                               // N
  float* dinv = (float*)(oend + N);                   // N
  int* gcursor = (int*)(dinv + N);                    // 1024       (zeroed)
  float* stats = (float*)(gcursor + 1024);            // 8 rep * 256 (zeroed)
  ushort* aggb = (ushort*)(stats + 2048);             // N*DD bf16 (optional)

  size_t need_aggb = (size_t)((char*)(aggb + (size_t)N * DD) - (char*)d_ws);
  if (ws_size < need_aggb) aggb = nullptr;  // fall back to f32 agg in d_out

  // one memset covers gcursor + stats (adjacent)
  hipMemsetAsync(gcursor, 0, 1024 * sizeof(int) + 2048 * sizeof(float), stream);

  int nchunk = (E + EPB - 1) / EPB;
  k_scatter_convw<<<nchunk + 1, 256, 0, stream>>>(src, dst, gcursor, stg, W, Wb,
                                                  E, NB, nchunk);

  k_binsort<<<NB, 256, 0, stream>>>(stg, gcursor, ssrc, offs, oend, dinv, N);

  int gG = (N + 63) / 64;
  k_gemm_mfma<<<gG, 256, 0, stream>>>(x, Wb, dinv, xwb, N);

  k_aggregate<<<2048, 256, 0, stream>>>(offs, oend, ssrc, dinv, b, xwb, out, aggb,
                                        stats, N);

  k_final<<<2048, 256, 0, stream>>>(out, aggb, x, b, gamma, beta, stats,
                                    1.0f / (float)N, N);
}